// Round 8
// baseline (207.328 us; speedup 1.0000x reference)
//
#include <hip/hip_runtime.h>
#include <hip/hip_bf16.h>

#define NBANK 131072
#define DF 1024
#define NB 64

typedef float f32x4 __attribute__((ext_vector_type(4)));
typedef short bf16x8 __attribute__((ext_vector_type(8)));

__device__ __forceinline__ unsigned short f2bf(float f) {
    union { float f; unsigned u; } c; c.f = f;
    unsigned u = c.u;
    return (unsigned short)((u + 0x7FFFu + ((u >> 16) & 1u)) >> 16);
}

// Kernel A: L2-normalize the 64 input rows; emit x_f32 (f32, for the update
// chain), MFMA-lane-ordered bf16 A-fragments, and the per-tile update-row
// bitmask urs[8192] (tile = blockIdx.x*128 + threadIdx.x; 64*128 = 8192).
__global__ __launch_bounds__(128) void knorm(const float* __restrict__ inputs,
                                             const int* __restrict__ indexes,
                                             float* __restrict__ x_f32,
                                             bf16x8* __restrict__ xfrag,
                                             unsigned* __restrict__ urs) {
    int m = blockIdx.x;
    int t = threadIdx.x;          // handles k = t*8 .. t*8+7
    __shared__ float red[2];
    __shared__ int sidx[NB];
    if (t < NB) sidx[t] = indexes[t];
    const f32x4* row = (const f32x4*)(inputs + (size_t)m * DF);
    f32x4 v0 = row[t * 2];
    f32x4 v1 = row[t * 2 + 1];
    float s = v0.x*v0.x + v0.y*v0.y + v0.z*v0.z + v0.w*v0.w
            + v1.x*v1.x + v1.y*v1.y + v1.z*v1.z + v1.w*v1.w;
    for (int o = 32; o > 0; o >>= 1) s += __shfl_xor(s, o);
    if ((t & 63) == 0) red[t >> 6] = s;
    __syncthreads();
    float tot = red[0] + red[1];
    float inv = 1.0f / fmaxf(sqrtf(tot), 1e-12f);
    v0 *= inv; v1 *= inv;
    f32x4* xr = (f32x4*)(x_f32 + (size_t)m * DF);
    xr[t * 2]     = v0;
    xr[t * 2 + 1] = v1;
    unsigned short h[8] = { f2bf(v0.x), f2bf(v0.y), f2bf(v0.z), f2bf(v0.w),
                            f2bf(v1.x), f2bf(v1.y), f2bf(v1.z), f2bf(v1.w) };
    int idx = ((m >> 4) * 32 + (t >> 2)) * 64 + (t & 3) * 16 + (m & 15);
    xfrag[idx] = *(bf16x8*)h;
    // per-tile update-row mask
    int tile = m * 128 + t;
    int j0 = tile * 16;
    unsigned mask = 0;
#pragma unroll 8
    for (int j = 0; j < NB; ++j) {
        unsigned d = (unsigned)(sidx[j] - j0);
        if (d < 16u) mask |= (1u << d);
    }
    urs[tile] = mask;
}

// Kernel B: fused sim GEMM + bank copy + sequential momentum update.
// One 16-row tile per block. Per-wave counted-vmcnt pipeline:
//   wave w issues 16 global_load_lds (rows 4w..4w+3, 4x1KB each, linear LDS)
//   then per row: s_waitcnt vmcnt(12) (oldest 4 = this row; 12 stay in
//   flight) -> ds_read 4 quarters -> pack bf16 (PRE-update) into the row's
//   own 4KB slot (first 2KB, XOR-swizzled) -> nt copy-store to outf.
//   Update-owned rows (wave-uniform, rare): vmcnt(0), pack, then the exact
//   sequential momentum chain with wave-level shfl reductions, store (no
//   plain copy for these rows -> no write race; post-drain all later
//   vmcnt(12) waits pass trivially).
//   Single lgkmcnt(0)+s_barrier (no vmcnt drain) -> 4 waves x 32 K-step
//   MFMA from the swizzled bf16 slots (row stride 4096) -> nt sim stores.
__global__ __launch_bounds__(256) void kmain(const float* __restrict__ features,
                                             const bf16x8* __restrict__ xfrag,
                                             const int* __restrict__ indexes,
                                             const float* __restrict__ x_f32,
                                             const unsigned* __restrict__ urs,
                                             float* __restrict__ sim,
                                             float* __restrict__ outf) {
    __shared__ __align__(16) unsigned char tile[65536];
    int t = threadIdx.x;
    int wave = t >> 6;
    int lane = t & 63;
    int j0 = blockIdx.x * 16;

    unsigned urmask = urs[blockIdx.x];
    // retire the urs load so the vmcnt FIFO holds exactly the 16 stage ops
    asm volatile("s_waitcnt vmcnt(0)" ::: "memory");

    // stage: this wave's 4 rows, 4 x 1KB per row, linear LDS layout
#pragma unroll
    for (int rr = 0; rr < 4; ++rr) {
        int r = wave * 4 + rr;
        const char* g = (const char*)(features + (size_t)(j0 + r) * DF);
#pragma unroll
        for (int q = 0; q < 4; ++q)
            __builtin_amdgcn_global_load_lds(
                (const __attribute__((address_space(1))) void*)(g + q * 1024 + lane * 16),
                (__attribute__((address_space(3))) void*)(tile + r * 4096 + q * 1024),
                16, 0, 0);
    }

    // per-row pipelined processing
#pragma unroll
    for (int rr = 0; rr < 4; ++rr) {
        int r = wave * 4 + rr;
        bool owned = (urmask >> r) & 1;          // wave-uniform
        if (owned) asm volatile("s_waitcnt vmcnt(0)" ::: "memory");
        else       asm volatile("s_waitcnt vmcnt(12)" ::: "memory");
        __builtin_amdgcn_sched_barrier(0);

        // readback: quarter q holds f32 elems q*256 + lane*4 .. +3
        f32x4 w0 = *(const f32x4*)(tile + r * 4096 +    0 + lane * 16);
        f32x4 w1 = *(const f32x4*)(tile + r * 4096 + 1024 + lane * 16);
        f32x4 w2 = *(const f32x4*)(tile + r * 4096 + 2048 + lane * 16);
        f32x4 w3 = *(const f32x4*)(tile + r * 4096 + 3072 + lane * 16);

        // pack PRE-update values -> bf16, XOR-swizzled, into row's own slot
        unsigned swz = (unsigned)((r & 7) << 4);
        {
            uint2 pk;
            pk.x = (unsigned)f2bf(w0.x) | ((unsigned)f2bf(w0.y) << 16);
            pk.y = (unsigned)f2bf(w0.z) | ((unsigned)f2bf(w0.w) << 16);
            *(uint2*)(tile + r * 4096 + (((unsigned)(   0 + lane * 8)) ^ swz)) = pk;
            pk.x = (unsigned)f2bf(w1.x) | ((unsigned)f2bf(w1.y) << 16);
            pk.y = (unsigned)f2bf(w1.z) | ((unsigned)f2bf(w1.w) << 16);
            *(uint2*)(tile + r * 4096 + (((unsigned)( 512 + lane * 8)) ^ swz)) = pk;
            pk.x = (unsigned)f2bf(w2.x) | ((unsigned)f2bf(w2.y) << 16);
            pk.y = (unsigned)f2bf(w2.z) | ((unsigned)f2bf(w2.w) << 16);
            *(uint2*)(tile + r * 4096 + (((unsigned)(1024 + lane * 8)) ^ swz)) = pk;
            pk.x = (unsigned)f2bf(w3.x) | ((unsigned)f2bf(w3.y) << 16);
            pk.y = (unsigned)f2bf(w3.z) | ((unsigned)f2bf(w3.w) << 16);
            *(uint2*)(tile + r * 4096 + (((unsigned)(1536 + lane * 8)) ^ swz)) = pk;
        }

        float* orow = outf + (size_t)(j0 + r) * DF + lane * 4;
        if (!owned) {
            __builtin_nontemporal_store(w0, (f32x4*)(orow      ));
            __builtin_nontemporal_store(w1, (f32x4*)(orow + 256));
            __builtin_nontemporal_store(w2, (f32x4*)(orow + 512));
            __builtin_nontemporal_store(w3, (f32x4*)(orow + 768));
        } else {
            // exact sequential momentum chain (wave-level reduction)
            int row = j0 + r;
            for (int j = 0; j < NB; ++j) {
                if (indexes[j] != row) continue;          // wave-uniform
                const float* xr = x_f32 + (size_t)j * DF + lane * 4;
                f32x4 x0 = *(const f32x4*)(xr      );
                f32x4 x1 = *(const f32x4*)(xr + 256);
                f32x4 x2 = *(const f32x4*)(xr + 512);
                f32x4 x3 = *(const f32x4*)(xr + 768);
                w0 = w0 * 0.2f + x0 * 0.8f;
                w1 = w1 * 0.2f + x1 * 0.8f;
                w2 = w2 * 0.2f + x2 * 0.8f;
                w3 = w3 * 0.2f + x3 * 0.8f;
                float s = w0.x*w0.x + w0.y*w0.y + w0.z*w0.z + w0.w*w0.w
                        + w1.x*w1.x + w1.y*w1.y + w1.z*w1.z + w1.w*w1.w
                        + w2.x*w2.x + w2.y*w2.y + w2.z*w2.z + w2.w*w2.w
                        + w3.x*w3.x + w3.y*w3.y + w3.z*w3.z + w3.w*w3.w;
                for (int o = 32; o > 0; o >>= 1) s += __shfl_xor(s, o);
                float inv = 1.0f / fmaxf(sqrtf(s), 1e-12f);
                w0 *= inv; w1 *= inv; w2 *= inv; w3 *= inv;
            }
            *(f32x4*)(orow      ) = w0;
            *(f32x4*)(orow + 256) = w1;
            *(f32x4*)(orow + 512) = w2;
            *(f32x4*)(orow + 768) = w3;
        }
    }

    // all packs visible; do NOT drain vmcnt (copy-stores stream on)
    asm volatile("s_waitcnt lgkmcnt(0)\n\ts_barrier" ::: "memory");

    // MFMA phase: B from swizzled bf16 slots (row stride 4096)
    const bf16x8* af = xfrag + (size_t)(wave * 32) * 64 + lane;
    unsigned bbase = (unsigned)(lane & 15) * 4096;
    unsigned bswz  = (unsigned)(lane & 7) << 4;
    unsigned bcol  = (unsigned)(lane >> 4) * 16;
    f32x4 acc = {0.f, 0.f, 0.f, 0.f};
#pragma unroll 8
    for (int ks = 0; ks < 32; ++ks) {
        bf16x8 a = af[ks * 64];
        bf16x8 b = *(const bf16x8*)(tile + bbase + (((unsigned)(ks * 64) + bcol) ^ bswz));
        acc = __builtin_amdgcn_mfma_f32_16x16x32_bf16(a, b, acc, 0, 0, 0);
    }
    int m0 = wave * 16 + (lane >> 4) * 4;
    int n = j0 + (lane & 15);
#pragma unroll
    for (int r = 0; r < 4; ++r)
        __builtin_nontemporal_store(acc[r] * 20.0f,
                                    sim + (size_t)(m0 + r) * NBANK + n);
}

extern "C" void kernel_launch(void* const* d_in, const int* in_sizes, int n_in,
                              void* d_out, int out_size, void* d_ws, size_t ws_size,
                              hipStream_t stream) {
    const float* inputs   = (const float*)d_in[0];
    const int*   indexes  = (const int*)d_in[1];
    const float* features = (const float*)d_in[2];
    float* sim  = (float*)d_out;                       // [64 * 131072]
    float* outf = sim + (size_t)NB * NBANK;            // [131072 * 1024]
    float*    x_f32 = (float*)d_ws;                                          // 256 KB
    bf16x8*   xfrag = (bf16x8*)((char*)d_ws + (size_t)NB * DF * 4);          // 128 KB
    unsigned* urs   = (unsigned*)((char*)d_ws + (size_t)NB * DF * 6);        // 32 KB

    knorm<<<NB, 128, 0, stream>>>(inputs, indexes, x_f32, xfrag, urs);
    kmain<<<NBANK / 16, 256, 0, stream>>>(features, xfrag, indexes, x_f32, urs, sim, outf);
}

// Round 9
// 187.663 us; speedup vs baseline: 1.1048x; 1.1048x over previous
//
#include <hip/hip_runtime.h>
#include <hip/hip_bf16.h>

#define NBANK 131072
#define DF 1024
#define NB 64
#define PINROWS 61440   // rows < PINROWS staged cacheable (240 MB pinned in L3);
                        // rows >= PINROWS staged with NT policy (stream past pin)

typedef float f32x4 __attribute__((ext_vector_type(4)));
typedef short bf16x8 __attribute__((ext_vector_type(8)));

__device__ __forceinline__ unsigned short f2bf(float f) {
    union { float f; unsigned u; } c; c.f = f;
    unsigned u = c.u;
    return (unsigned short)((u + 0x7FFFu + ((u >> 16) & 1u)) >> 16);
}

// Kernel A: L2-normalize the 64 input rows; emit x_f32 (f32, for the update
// chain), MFMA-lane-ordered bf16 A-fragments, and the per-tile update-row
// bitmask urs[8192] (tile = blockIdx.x*128 + threadIdx.x; 64*128 = 8192).
__global__ __launch_bounds__(128) void knorm(const float* __restrict__ inputs,
                                             const int* __restrict__ indexes,
                                             float* __restrict__ x_f32,
                                             bf16x8* __restrict__ xfrag,
                                             unsigned* __restrict__ urs) {
    int m = blockIdx.x;
    int t = threadIdx.x;          // handles k = t*8 .. t*8+7
    __shared__ float red[2];
    __shared__ int sidx[NB];
    if (t < NB) sidx[t] = indexes[t];
    const f32x4* row = (const f32x4*)(inputs + (size_t)m * DF);
    f32x4 v0 = row[t * 2];
    f32x4 v1 = row[t * 2 + 1];
    float s = v0.x*v0.x + v0.y*v0.y + v0.z*v0.z + v0.w*v0.w
            + v1.x*v1.x + v1.y*v1.y + v1.z*v1.z + v1.w*v1.w;
    for (int o = 32; o > 0; o >>= 1) s += __shfl_xor(s, o);
    if ((t & 63) == 0) red[t >> 6] = s;
    __syncthreads();
    float tot = red[0] + red[1];
    float inv = 1.0f / fmaxf(sqrtf(tot), 1e-12f);
    v0 *= inv; v1 *= inv;
    f32x4* xr = (f32x4*)(x_f32 + (size_t)m * DF);
    xr[t * 2]     = v0;
    xr[t * 2 + 1] = v1;
    unsigned short h[8] = { f2bf(v0.x), f2bf(v0.y), f2bf(v0.z), f2bf(v0.w),
                            f2bf(v1.x), f2bf(v1.y), f2bf(v1.z), f2bf(v1.w) };
    int idx = ((m >> 4) * 32 + (t >> 2)) * 64 + (t & 3) * 16 + (m & 15);
    xfrag[idx] = *(bf16x8*)h;
    // per-tile update-row mask
    int tile = m * 128 + t;
    int j0 = tile * 16;
    unsigned mask = 0;
#pragma unroll 8
    for (int j = 0; j < NB; ++j) {
        unsigned d = (unsigned)(sidx[j] - j0);
        if (d < 16u) mask |= (1u << d);
    }
    urs[tile] = mask;
}

// Kernel B (R7 structure, policy-split staging): fused sim GEMM + bank copy
// + sequential momentum update. One 16-row tile per block.
//   stage: 64 x global_load_lds (1 KB each) DMA the 64 KB f32 tile to LDS,
//          aux=0 (cacheable/pin) below PINROWS, aux=2 (NT/stream) above
//   __syncthreads: tile complete
//   readback v[16] -> __syncthreads -> pack bf16 XOR-swizzled (LDS reuse)
//   __syncthreads -> nt outf copy-stores (fire-and-forget, overlap MFMA)
//   -> 4 waves x 32 K-step MFMA -> nt sim stores
//   phase C (rare): exact sequential momentum chain from v[p].
__global__ __launch_bounds__(256) void kmain(const float* __restrict__ features,
                                             const bf16x8* __restrict__ xfrag,
                                             const int* __restrict__ indexes,
                                             const float* __restrict__ x_f32,
                                             const unsigned* __restrict__ urs,
                                             float* __restrict__ sim,
                                             float* __restrict__ outf) {
    __shared__ __align__(16) unsigned char tile[65536];
    __shared__ float red[4];
    int t = threadIdx.x;          // owns within-row byte chunk t*16 .. t*16+15
    int wave = t >> 6;
    int lane = t & 63;
    int j0 = blockIdx.x * 16;
    unsigned urmask = urs[blockIdx.x];

    // stage: wave w DMAs rows 4w..4w+3 (4 x 1KB per row), linear LDS layout;
    // cache policy split is block-uniform (aux must be a literal constant)
    if (j0 < PINROWS) {
#pragma unroll
        for (int rr = 0; rr < 4; ++rr) {
            int r = wave * 4 + rr;
            const char* g = (const char*)(features + (size_t)(j0 + r) * DF);
#pragma unroll
            for (int q = 0; q < 4; ++q)
                __builtin_amdgcn_global_load_lds(
                    (const __attribute__((address_space(1))) void*)(g + q * 1024 + lane * 16),
                    (__attribute__((address_space(3))) void*)(tile + r * 4096 + q * 1024),
                    16, 0, 0);
        }
    } else {
#pragma unroll
        for (int rr = 0; rr < 4; ++rr) {
            int r = wave * 4 + rr;
            const char* g = (const char*)(features + (size_t)(j0 + r) * DF);
#pragma unroll
            for (int q = 0; q < 4; ++q)
                __builtin_amdgcn_global_load_lds(
                    (const __attribute__((address_space(1))) void*)(g + q * 1024 + lane * 16),
                    (__attribute__((address_space(3))) void*)(tile + r * 4096 + q * 1024),
                    16, 0, 2);   // NT: stream past the L3 pin
        }
    }
    __syncthreads();              // own vmcnt drained + barrier: tile complete

    // readback my column-chunk of every row
    f32x4 v[16];
#pragma unroll
    for (int p = 0; p < 16; ++p)
        v[p] = *(const f32x4*)(tile + p * 4096 + t * 16);
    __syncthreads();              // all reads done; LDS reusable

    // pack bf16 -> swizzled tile (no global stores yet)
#pragma unroll
    for (int p = 0; p < 16; ++p) {
        unsigned lo = (unsigned)f2bf(v[p].x) | ((unsigned)f2bf(v[p].y) << 16);
        unsigned hi = (unsigned)f2bf(v[p].z) | ((unsigned)f2bf(v[p].w) << 16);
        uint2 pk; pk.x = lo; pk.y = hi;
        unsigned off = (unsigned)(p * 2048) + (((unsigned)(t * 8)) ^ ((unsigned)(p & 7) << 4));
        *(uint2*)(tile + off) = pk;
    }
    __syncthreads();

    // outf copy-stores: issued after the last barrier -> never drained,
    // overlap with the MFMA phase below
#pragma unroll
    for (int p = 0; p < 16; ++p)
        __builtin_nontemporal_store(v[p], (f32x4*)(outf + (size_t)(j0 + p) * DF) + t);

    // MFMA phase
    const bf16x8* af = xfrag + (size_t)(wave * 32) * 64 + lane;
    unsigned bbase = (unsigned)(lane & 15) * 2048;
    unsigned bswz  = (unsigned)(lane & 7) << 4;
    unsigned bcol  = (unsigned)(lane >> 4) * 16;
    f32x4 acc = {0.f, 0.f, 0.f, 0.f};
#pragma unroll 8
    for (int ks = 0; ks < 32; ++ks) {
        bf16x8 a = af[ks * 64];
        bf16x8 b = *(const bf16x8*)(tile + bbase + (((unsigned)(ks * 64) + bcol) ^ bswz));
        acc = __builtin_amdgcn_mfma_f32_16x16x32_bf16(a, b, acc, 0, 0, 0);
    }
    int m0 = wave * 16 + (lane >> 4) * 4;
    int n = j0 + (lane & 15);
#pragma unroll
    for (int r = 0; r < 4; ++r)
        __builtin_nontemporal_store(acc[r] * 20.0f,
                                    sim + (size_t)(m0 + r) * NBANK + n);

    // phase C: sequential momentum chain (urmask is block-uniform);
    // cur inits from v[p]; overwrites this thread's own copy-store
    // (same thread, same address -> program order gives the final value)
    if (urmask) {
        __syncthreads();
        for (int p = 0; p < 16; ++p) {
            if (!((urmask >> p) & 1)) continue;      // uniform
            int row = j0 + p;
            f32x4 cur = v[p];
            for (int j = 0; j < NB; ++j) {
                if (indexes[j] != row) continue;     // uniform
                f32x4 xv = *((const f32x4*)(x_f32 + (size_t)j * DF) + t);
                cur = cur * 0.2f + xv * 0.8f;
                float s = cur.x*cur.x + cur.y*cur.y + cur.z*cur.z + cur.w*cur.w;
                for (int o = 32; o > 0; o >>= 1) s += __shfl_xor(s, o);
                if ((t & 63) == 0) red[t >> 6] = s;
                __syncthreads();
                float tot = red[0] + red[1] + red[2] + red[3];
                __syncthreads();
                float inv = 1.0f / fmaxf(sqrtf(tot), 1e-12f);
                cur *= inv;
            }
            *((f32x4*)(outf + (size_t)row * DF) + t) = cur;
        }
    }
}

extern "C" void kernel_launch(void* const* d_in, const int* in_sizes, int n_in,
                              void* d_out, int out_size, void* d_ws, size_t ws_size,
                              hipStream_t stream) {
    const float* inputs   = (const float*)d_in[0];
    const int*   indexes  = (const int*)d_in[1];
    const float* features = (const float*)d_in[2];
    float* sim  = (float*)d_out;                       // [64 * 131072]
    float* outf = sim + (size_t)NB * NBANK;            // [131072 * 1024]
    float*    x_f32 = (float*)d_ws;                                          // 256 KB
    bf16x8*   xfrag = (bf16x8*)((char*)d_ws + (size_t)NB * DF * 4);          // 128 KB
    unsigned* urs   = (unsigned*)((char*)d_ws + (size_t)NB * DF * 6);        // 32 KB

    knorm<<<NB, 128, 0, stream>>>(inputs, indexes, x_f32, xfrag, urs);
    kmain<<<NBANK / 16, 256, 0, stream>>>(features, xfrag, indexes, x_f32, urs, sim, outf);
}